// Round 12
// baseline (411.700 us; speedup 1.0000x reference)
//
#include <hip/hip_runtime.h>
#include <math.h>

#define Hn 50
#define Dn 8
#define Tn 512
#define BB 8               // batches per block
#define NBLK 256           // 2048/8 -> 1 block/CU
#define KST 136            // row stride (shorts). MUST be 0 mod 8 (16B-aligned
                           // b128 reads; r21's KST=140 split every load, 2.4x).
                           // row+8 bank alias accepted (r22: conflicts not the wall).

typedef __attribute__((ext_vector_type(8))) short short8;   // 8 bf16 (4 VGPRs)
typedef __attribute__((ext_vector_type(4))) float f32x4;

__device__ __forceinline__ float fexp2_(float x) {
#if __has_builtin(__builtin_amdgcn_exp2f)
    return __builtin_amdgcn_exp2f(x);
#else
    return exp2f(x);
#endif
}
__device__ __forceinline__ float frcp_(float x) {
#if __has_builtin(__builtin_amdgcn_rcpf)
    return __builtin_amdgcn_rcpf(x);
#else
    return 1.0f / x;
#endif
}
__device__ __forceinline__ float bf2f(short s) {
    return __uint_as_float(((unsigned)(unsigned short)s) << 16);
}
// truncation split: v = hi + lo + O(2^-17 v)
__device__ __forceinline__ void split_bf(float v, short& hi, short& lo) {
    hi = (short)(__float_as_uint(v) >> 16);
    const float r = v - bf2f(hi);
    lo = (short)(__float_as_uint(r) >> 16);
}
// Pre-scaled act: gates arrive as G = -1.4427*(Wx+b) (i,f,o) / -2.8854*(Wx+b) (g).
// sigmoid(x) = 1/(1+2^G); tanh(x) = 2/(1+2^G) - 1.
__device__ __forceinline__ float lstm_cell4s(const f32x4 g4, float& c) {
    const float si = frcp_(1.0f + fexp2_(g4.x));
    const float sf = frcp_(1.0f + fexp2_(g4.y));
    const float so = frcp_(1.0f + fexp2_(g4.w));
    const float tg = 2.0f * frcp_(1.0f + fexp2_(g4.z)) - 1.0f;
    c = sf * c + si * tg;
    const float tr = frcp_(1.0f + fexp2_(-2.88539008f * c));
    return so * (2.0f * tr - 1.0f);
}
// lane i <-> i^8 via DPP row_ror:8 (16-lane rows): pure VALU, no LDS traffic.
__device__ __forceinline__ float xor8_(float v) {
#if __has_builtin(__builtin_amdgcn_update_dpp)
    return __int_as_float(__builtin_amdgcn_update_dpp(
        0, __float_as_int(v), 0x128 /*row_ror:8*/, 0xF, 0xF, true));
#else
    return __shfl_xor(v, 8, 64);
#endif
}

// ============================================================================
// r24 = r23 (best: 383us steady) + r22's CONSOLIDATED SLOT MAP, spill-proofed.
// r23 accounting (1795 cy/CU/step): matrix 757, LDS convoy ~730 (58KB reads +
// 274 conflict-cy), VALU 386/SIMD -> largest reducible serial chunk = the
// post-barrier LDS read convoy. r22 proved consolidation cuts reads -31% /
// conflicts -41% but was corrupted by spill (compiler chose 64-VGPR budget;
// 2.7MB scratch + LDS spill blocks). Here: __launch_bounds__(1024,4) pins the
// 128-reg budget; worst wave (2xL1) = 64 AGPR weights + 8 acc + ~40 VGPR
// ~= 112 < 128 (r23 measured VGPR_Count=40: weights live in AGPRs).
// Slot map (26 tiles; wave i -> SIMD i&3, per-SIMD MFMA 40/40/40/36):
//   w0-5 : 2 L1 {2w,2w+1}   (NBF=4, 4KB/step read)  16 MFMA
//   w6   : 1 L1 {12} + 1 L0 {0}  (NBF=4)            12 MFMA
//   w7-11: 2 L0 {2(w-7)+1, 2(w-7)+2}  (NBF=2, 2KB)   8 MFMA
//   w12  : idle (barrier only)
//   w13  : x-duty only
//   w14  : 1 L0 {11}   w15: 1 L0 {12}  (NBF=2)       4 MFMA
// Total LDS read 42KB/step vs r23's 58KB (-28%).
// Everything else identical to r23: diet (DPP xor-8, scales-in-W, bias-in-K,
// zero-C start), KST=136, no setprio, single 8-deep L1 chain, 1 barrier/step.
// K layout: k 0..49 = h0 | 50..57 = x | 58..62 = 0 | 63 = one | 64..113 = h1 |
//           114..126 = 0 | 127 = one.
// C/D: n=lane&15 (batch: cols 0..7 hi, 8..15 lo), m=(lane>>4)*4+reg = the
// (i,f,g,o) of cell 4T+quad -> act fully in-register.
// ============================================================================

template<int NL1, int NL0, bool XD>
__device__ __forceinline__ void run_loop(
    const int* l1T, const int* l0T,
    int b0, int lane, int quad, int col,
    short (*bP)[16][KST], float* h1f, const float* x,
    const float* Wih0, const float* Whh0, const float* bih0, const float* bhh0,
    const float* Wih1, const float* Whh1, const float* bih1, const float* bhh1)
{
    constexpr int NS = NL1 + NL0;
    constexpr int NPAIR = (NS + 1) / 2;
    constexpr int NBF = (NL1 > 0) ? 4 : 2;
    constexpr int NSg = (NS > 0) ? NS : 1;       // zero-size array guards
    constexpr int NPg = (NPAIR > 0) ? NPAIR : 1;

    short8 W1[NL1 > 0 ? NL1 : 1][4][2];   // [slot][kstep][hi/lo]
    short8 W0[NL0 > 0 ? NL0 : 1][2][2];
    int    kb[NSg];      // k index base for h-write: layer*64 + 4*T
    int    cellb[NSg];   // cell base: 4*T

    // Gate-row scale folded into weights: row's gate type = col&3 (i,f,g,o);
    // g-gate (==2) carries tanh's 2x argument factor.
    const float sc = ((col & 3) == 2) ? -2.88539008f : -1.44269504f;

    // ---- stationary A-side weights: lane holds W[m=col][k=32s+quad*8+j] ----
    #pragma unroll
    for (int i = 0; i < NL1; ++i) {
        const int T = l1T[i];
        const int ng = T * 16 + col, cl = ng >> 2;
        const bool on = (cl < Hn);
        const int grow = (col & 3) * Hn + cl;
        #pragma unroll
        for (int s = 0; s < 4; ++s)
            #pragma unroll
            for (int j = 0; j < 8; ++j) {
                const int k = 32 * s + quad * 8 + j;
                float v = 0.f;
                if (on) {
                    if (k < Hn)                      v = Wih1[grow * Hn + k];
                    else if (k >= 64 && k < 64 + Hn) v = Whh1[grow * Hn + (k - 64)];
                    else if (k == 127)               v = bih1[grow] + bhh1[grow];
                }
                v *= sc;
                short hi, lo; split_bf(v, hi, lo);
                W1[i][s][0][j] = hi; W1[i][s][1][j] = lo;
            }
        kb[i] = 64 + 4 * T; cellb[i] = 4 * T;
    }
    #pragma unroll
    for (int i = 0; i < NL0; ++i) {
        const int T = l0T[i];
        const int ng = T * 16 + col, cl = ng >> 2;
        const bool on = (cl < Hn);
        const int grow = (col & 3) * Hn + cl;
        #pragma unroll
        for (int s = 0; s < 2; ++s)
            #pragma unroll
            for (int j = 0; j < 8; ++j) {
                const int k = 32 * s + quad * 8 + j;
                float v = 0.f;
                if (on) {
                    if (k < Hn)           v = Whh0[grow * Hn + k];
                    else if (k < Hn + Dn) v = Wih0[grow * Dn + (k - Hn)];
                    else if (k == 63)     v = bih0[grow] + bhh0[grow];
                }
                v *= sc;
                short hi, lo; split_bf(v, hi, lo);
                W0[i][s][0][j] = hi; W0[i][s][1][j] = lo;
            }
        kb[NL1 + i] = 4 * T; cellb[NL1 + i] = 4 * T;
    }

    // ---- hoisted loop invariants ----
    const short* base0 = &bP[0][0][0];
    const short* base1 = &bP[1][0][0];
    int rdo[NBF];
    #pragma unroll
    for (int s = 0; s < NBF; ++s) rdo[s] = col * KST + 32 * s + quad * 8;

    int  wofH[NPg], wofL[NPg], wofS[NPg];
    bool actOK[NPg], lagged[NPg];
    #pragma unroll
    for (int p = 0; p < NPAIR; ++p) {
        const int ia = 2 * p;
        const bool hasB = (ia + 1 < NS);
        const int slot = (hasB && col >= 8) ? ia + 1 : ia;
        const int cell = cellb[slot] + quad;
        const int kc   = kb[slot] + quad;
        lagged[p] = (slot < NL1);
        actOK[p]  = (cell < Hn);
        wofH[p] = (col & 7) * KST + kc;
        wofL[p] = wofH[p] + 8 * KST;
        wofS[p] = col * KST + kc;
    }

    float c[NPg];
    #pragma unroll
    for (int p = 0; p < NPg; ++p) c[p] = 0.f;
    const f32x4 z4 = {0.f, 0.f, 0.f, 0.f};   // persistent zero C operand

    const float* xp = XD ? (x + (size_t)(b0 + (lane >> 3)) * Tn * Dn + (lane & 7))
                         : (const float*)nullptr;
    int xwH = 0, xwL = 0;
    if (XD) {
        const int xr = lane >> 3, xd = lane & 7;
        xwH = xr * KST + Hn + xd;
        xwL = xwH + 8 * KST;
    }

    // ================= main loop: one phase (one barrier) per timestep ======
    for (int t = 0; t < Tn; ++t) {
        float xv = 0.f;
        if (XD) { if (t + 1 < Tn) xv = xp[(size_t)(t + 1) * Dn]; }   // issue early

        const short* rb = (t & 1) ? base1 : base0;      // scalar selects (t uniform)
        short* wb = (short*)((t & 1) ? base0 : base1);

        if constexpr (NS > 0) {
            // B-side fragments: compile-time order (rule #20: no runtime idx)
            short8 BF[NBF];
            #pragma unroll
            for (int s = 0; s < NBF; ++s)
                BF[s] = *(const short8*)&rb[rdo[s]];

            f32x4 acc[NSg];
            #pragma unroll
            for (int i = 0; i < NL1; ++i) {
                f32x4 a = __builtin_amdgcn_mfma_f32_16x16x32_bf16(W1[i][0][0], BF[0], z4, 0, 0, 0);
                a = __builtin_amdgcn_mfma_f32_16x16x32_bf16(W1[i][0][1], BF[0], a, 0, 0, 0);
                a = __builtin_amdgcn_mfma_f32_16x16x32_bf16(W1[i][1][0], BF[1], a, 0, 0, 0);
                a = __builtin_amdgcn_mfma_f32_16x16x32_bf16(W1[i][1][1], BF[1], a, 0, 0, 0);
                a = __builtin_amdgcn_mfma_f32_16x16x32_bf16(W1[i][2][0], BF[2], a, 0, 0, 0);
                a = __builtin_amdgcn_mfma_f32_16x16x32_bf16(W1[i][2][1], BF[2], a, 0, 0, 0);
                a = __builtin_amdgcn_mfma_f32_16x16x32_bf16(W1[i][3][0], BF[3], a, 0, 0, 0);
                a = __builtin_amdgcn_mfma_f32_16x16x32_bf16(W1[i][3][1], BF[3], a, 0, 0, 0);
                acc[i] = a;
            }
            #pragma unroll
            for (int i = 0; i < NL0; ++i) {
                const int ii = NL1 + i;
                f32x4 a = __builtin_amdgcn_mfma_f32_16x16x32_bf16(W0[i][0][0], BF[0], z4, 0, 0, 0);
                a = __builtin_amdgcn_mfma_f32_16x16x32_bf16(W0[i][0][1], BF[0], a, 0, 0, 0);
                a = __builtin_amdgcn_mfma_f32_16x16x32_bf16(W0[i][1][0], BF[1], a, 0, 0, 0);
                a = __builtin_amdgcn_mfma_f32_16x16x32_bf16(W0[i][1][1], BF[1], a, 0, 0, 0);
                acc[ii] = a;
            }

            // ---- in-register act: paired slots, DPP xor-8 merge ----
            #pragma unroll
            for (int p = 0; p < NPAIR; ++p) {
                const int ia = 2 * p;
                const bool hasB = (ia + 1 < NS);
                f32x4 g;
                #pragma unroll
                for (int r = 0; r < 4; ++r) {
                    if (hasB) {
                        const float u = (col < 8) ? acc[ia][r]     : acc[ia + 1][r];
                        const float v = (col < 8) ? acc[ia + 1][r] : acc[ia][r];
                        g[r] = u + xor8_(v);
                    } else {
                        g[r] = acc[ia][r] + xor8_(acc[ia][r]);
                    }
                }
                const bool doAct = actOK[p] && ((t >= 1) || !lagged[p]);  // L1 lags 1
                if (doAct) {
                    const float h = lstm_cell4s(g, c[p]);
                    short hi, lo; split_bf(h, hi, lo);
                    if (hasB) { wb[wofH[p]] = hi; wb[wofL[p]] = lo; }
                    else      { wb[wofS[p]] = (col < 8) ? hi : lo; }
                }
            }
        }
        if (XD) {
            if (t + 1 < Tn) {
                short hi, lo; split_bf(xv, hi, lo);
                wb[xwH] = hi;
                wb[xwL] = lo;
            }
        }
        __syncthreads();
    }

    // ======== epilogue phase: gates1(Tn-1) + act1 -> h1f (fp32) ========
    if constexpr (NL1 > 0) {
        const short* rb = base0;   // Tn even -> bP[0]
        short8 BF[4];
        #pragma unroll
        for (int s = 0; s < 4; ++s)
            BF[s] = *(const short8*)&rb[rdo[s]];
        f32x4 accE[NL1];
        #pragma unroll
        for (int i = 0; i < NL1; ++i) {
            f32x4 a = __builtin_amdgcn_mfma_f32_16x16x32_bf16(W1[i][0][0], BF[0], z4, 0, 0, 0);
            a = __builtin_amdgcn_mfma_f32_16x16x32_bf16(W1[i][0][1], BF[0], a, 0, 0, 0);
            a = __builtin_amdgcn_mfma_f32_16x16x32_bf16(W1[i][1][0], BF[1], a, 0, 0, 0);
            a = __builtin_amdgcn_mfma_f32_16x16x32_bf16(W1[i][1][1], BF[1], a, 0, 0, 0);
            a = __builtin_amdgcn_mfma_f32_16x16x32_bf16(W1[i][2][0], BF[2], a, 0, 0, 0);
            a = __builtin_amdgcn_mfma_f32_16x16x32_bf16(W1[i][2][1], BF[2], a, 0, 0, 0);
            a = __builtin_amdgcn_mfma_f32_16x16x32_bf16(W1[i][3][0], BF[3], a, 0, 0, 0);
            a = __builtin_amdgcn_mfma_f32_16x16x32_bf16(W1[i][3][1], BF[3], a, 0, 0, 0);
            accE[i] = a;
        }
        #pragma unroll
        for (int p = 0; p < NPAIR; ++p) {
            const int ia = 2 * p;
            if (ia < NL1) {
                const bool bL1 = (ia + 1 < NL1);
                f32x4 g;
                #pragma unroll
                for (int r = 0; r < 4; ++r) {
                    if (bL1) {
                        const float u = (col < 8) ? accE[ia][r]     : accE[ia + 1][r];
                        const float v = (col < 8) ? accE[ia + 1][r] : accE[ia][r];
                        g[r] = u + xor8_(v);
                    } else {
                        g[r] = accE[ia][r] + xor8_(accE[ia][r]);
                    }
                }
                int cell; bool mine;
                if (bL1) { cell = ((col < 8) ? cellb[ia] : cellb[ia + 1]) + quad; mine = true; }
                else     { cell = cellb[ia] + quad;                               mine = (col < 8); }
                if (mine && cell < Hn) {
                    const float h = lstm_cell4s(g, c[p]);
                    h1f[cell * 8 + (col & 7)] = h;
                }
            }
        }
    }
}

__global__ __launch_bounds__(1024, 4) void lstm2_kernel(
    const float* __restrict__ x,
    const float* __restrict__ Wih0, const float* __restrict__ Whh0,
    const float* __restrict__ bih0, const float* __restrict__ bhh0,
    const float* __restrict__ Wih1, const float* __restrict__ Whh1,
    const float* __restrict__ bih1, const float* __restrict__ bhh1,
    const float* __restrict__ Wlin, const float* __restrict__ blin,
    float* __restrict__ out)
{
    const int tid  = threadIdx.x;     // 0..1023
    const int b0   = blockIdx.x * BB;
    // readfirstlane: wave index SGPR-uniform so shape dispatch is scalar —
    // __syncthreads lives inside the branches (equal counts in all arms).
    const int w    = __builtin_amdgcn_readfirstlane(tid >> 6);   // 0..15
    const int lane = tid & 63;
    const int quad = lane >> 4;
    const int col  = lane & 15;

    __shared__ __align__(16) short bP[2][16][KST];   // double-buffered h/x pack
    __shared__ float h1f[Hn * 8];                    // fp32 h1 at t=Tn-1

    // ---- init: zero both buffers; plant bias-ones; stage x(0) ----
    for (int i = tid; i < 2 * 16 * KST; i += 1024) (&bP[0][0][0])[i] = 0;
    __syncthreads();
    if (tid < 8) {               // bf16(1.0) at k=63 / k=127, hi rows only
        const short one = (short)0x3F80;
        bP[0][tid][63]  = one;  bP[1][tid][63]  = one;
        bP[0][tid][127] = one;  bP[1][tid][127] = one;
    } else if (tid >= 64 && tid < 128) {
        const int q = tid - 64;
        const int xb = q >> 3, xd = q & 7;
        const float f = x[((size_t)(b0 + xb) * Tn + 0) * Dn + xd];
        short hi, lo; split_bf(f, hi, lo);
        bP[0][xb][Hn + xd]     = hi;
        bP[0][xb + 8][Hn + xd] = lo;
    }
    __syncthreads();

    // Consolidated+balanced map (per-SIMD MFMA 40/40/40/36, reads 42KB/step):
    if (w < 6) {
        const int l1t[2] = {2 * w, 2 * w + 1};        // L1 tiles 0..11
        run_loop<2, 0, false>(l1t, nullptr, b0, lane, quad, col, bP, h1f, x,
                              Wih0, Whh0, bih0, bhh0, Wih1, Whh1, bih1, bhh1);
    } else if (w == 6) {
        const int l1t[1] = {12};                      // L1 tile 12
        const int l0t[1] = {0};                       // L0 tile 0
        run_loop<1, 1, false>(l1t, l0t, b0, lane, quad, col, bP, h1f, x,
                              Wih0, Whh0, bih0, bhh0, Wih1, Whh1, bih1, bhh1);
    } else if (w < 12) {
        const int l0t[2] = {2 * (w - 7) + 1, 2 * (w - 7) + 2};   // L0 1..10
        run_loop<0, 2, false>(nullptr, l0t, b0, lane, quad, col, bP, h1f, x,
                              Wih0, Whh0, bih0, bhh0, Wih1, Whh1, bih1, bhh1);
    } else if (w == 12) {
        run_loop<0, 0, false>(nullptr, nullptr, b0, lane, quad, col, bP, h1f, x,
                              Wih0, Whh0, bih0, bhh0, Wih1, Whh1, bih1, bhh1);
    } else if (w == 13) {
        run_loop<0, 0, true>(nullptr, nullptr, b0, lane, quad, col, bP, h1f, x,
                             Wih0, Whh0, bih0, bhh0, Wih1, Whh1, bih1, bhh1);
    } else if (w == 14) {
        const int l0t[1] = {11};
        run_loop<0, 1, false>(nullptr, l0t, b0, lane, quad, col, bP, h1f, x,
                              Wih0, Whh0, bih0, bhh0, Wih1, Whh1, bih1, bhh1);
    } else {
        const int l0t[1] = {12};
        run_loop<0, 1, false>(nullptr, l0t, b0, lane, quad, col, bP, h1f, x,
                              Wih0, Whh0, bih0, bhh0, Wih1, Whh1, bih1, bhh1);
    }
    __syncthreads();

    // ---- head: out[b] = h1_last . Wlin + blin (fp32 path) ----
    if (tid < BB) {
        float o = blin[0];
        #pragma unroll
        for (int k = 0; k < Hn; ++k) o += Wlin[k] * h1f[k * 8 + tid];
        out[b0 + tid] = o;
    }
}

extern "C" void kernel_launch(void* const* d_in, const int* in_sizes, int n_in,
                              void* d_out, int out_size, void* d_ws, size_t ws_size,
                              hipStream_t stream) {
    const float* x    = (const float*)d_in[0];
    const float* Wih0 = (const float*)d_in[1];
    const float* Whh0 = (const float*)d_in[2];
    const float* bih0 = (const float*)d_in[3];
    const float* bhh0 = (const float*)d_in[4];
    const float* Wih1 = (const float*)d_in[5];
    const float* Whh1 = (const float*)d_in[6];
    const float* bih1 = (const float*)d_in[7];
    const float* bhh1 = (const float*)d_in[8];
    const float* Wlin = (const float*)d_in[9];
    const float* blin = (const float*)d_in[10];
    float* out = (float*)d_out;

    lstm2_kernel<<<NBLK, 1024, 0, stream>>>(x, Wih0, Whh0, bih0, bhh0,
                                            Wih1, Whh1, bih1, bhh1,
                                            Wlin, blin, out);
}